// Round 1
// baseline (2089.915 us; speedup 1.0000x reference)
//
#include <hip/hip_runtime.h>
#include <hip/hip_bf16.h>
#include <math.h>

// Problem constants
#define NB     4          // batch
#define CDIM   256        // d_model
#define HWDIM  16384      // 128*128 tokens per image
#define LTOK   16384
#define NH     8
#define HD     32
#define FF     512
#define MTOK   (NB * LTOK)   // 65536 total tokens
#define NLAYER 4

typedef __bf16 bf16x8 __attribute__((ext_vector_type(8)));
typedef __bf16 bf16x4 __attribute__((ext_vector_type(4)));
typedef float  floatx4 __attribute__((ext_vector_type(4)));

// ---------------------------------------------------------------------------
// Tiled transpose: in [R, Cc] -> out [Cc, R], batched over blockIdx.z
// ---------------------------------------------------------------------------
__global__ __launch_bounds__(256)
void transpose_k(const float* __restrict__ in, float* __restrict__ out,
                 int R, int Cc, long long in_bstride, long long out_bstride)
{
    __shared__ float tile[32][33];
    const float* ib = in  + (long long)blockIdx.z * in_bstride;
    float*       ob = out + (long long)blockIdx.z * out_bstride;
    int c0 = blockIdx.x * 32;
    int r0 = blockIdx.y * 32;
    int tx = threadIdx.x;   // 0..31
    int ty = threadIdx.y;   // 0..7
#pragma unroll
    for (int i = 0; i < 32; i += 8)
        tile[ty + i][tx] = ib[(long long)(r0 + ty + i) * Cc + c0 + tx];
    __syncthreads();
#pragma unroll
    for (int i = 0; i < 32; i += 8)
        ob[(long long)(c0 + ty + i) * R + r0 + tx] = tile[tx][ty + i];
}

// ---------------------------------------------------------------------------
// MFMA bf16 GEMM:  C[M,O] = act( A[M,K] @ B[O,K]^T + bias[O] )
// A, B fp32 in global; converted to bf16 while staging to LDS.
// ACT: 0 = none, 1 = elu(x)+1, 2 = relu
// Block 256 threads = 4 waves; tile 128x128, BK=32 (one mfma K-step).
// ---------------------------------------------------------------------------
template <int ACT>
__global__ __launch_bounds__(256)
void gemm_bias_act(const float* __restrict__ A, const float* __restrict__ B,
                   const float* __restrict__ bias, float* __restrict__ C,
                   int M, int K, int O)
{
    // LDS: [row][k] with row stride 40 bf16 (80 B = 5*16 B -> b128-aligned,
    // 2-way bank aliasing which is free on gfx950)
    __shared__ __bf16 Asl[128 * 40];
    __shared__ __bf16 Bsl[128 * 40];

    const int tid  = threadIdx.x;
    const int m0   = blockIdx.x * 128;
    const int n0   = blockIdx.y * 128;
    const int lane = tid & 63;
    const int wave = tid >> 6;
    const int wm   = (wave & 1) * 64;
    const int wn   = (wave >> 1) * 64;
    const int l15  = lane & 15;
    const int quad = lane >> 4;

    floatx4 acc[4][4];
#pragma unroll
    for (int i = 0; i < 4; ++i)
#pragma unroll
        for (int j = 0; j < 4; ++j)
            acc[i][j] = (floatx4){0.f, 0.f, 0.f, 0.f};

    for (int k0 = 0; k0 < K; k0 += 32) {
        __syncthreads();
        // stage A tile: 128 rows x 32 k = 1024 float4 loads, 4 per thread
#pragma unroll
        for (int i = 0; i < 4; ++i) {
            int flat = tid + i * 256;
            int row  = flat >> 3;
            int kq   = flat & 7;
            float4 f = *(const float4*)&A[(long long)(m0 + row) * K + k0 + kq * 4];
            bf16x4 h;
            h[0] = (__bf16)f.x; h[1] = (__bf16)f.y;
            h[2] = (__bf16)f.z; h[3] = (__bf16)f.w;
            *(bf16x4*)&Asl[row * 40 + kq * 4] = h;
        }
#pragma unroll
        for (int i = 0; i < 4; ++i) {
            int flat = tid + i * 256;
            int row  = flat >> 3;
            int kq   = flat & 7;
            float4 f = *(const float4*)&B[(long long)(n0 + row) * K + k0 + kq * 4];
            bf16x4 h;
            h[0] = (__bf16)f.x; h[1] = (__bf16)f.y;
            h[2] = (__bf16)f.z; h[3] = (__bf16)f.w;
            *(bf16x4*)&Bsl[row * 40 + kq * 4] = h;
        }
        __syncthreads();

        bf16x8 af[4], bfr[4];
#pragma unroll
        for (int mt = 0; mt < 4; ++mt)
            af[mt] = *(const bf16x8*)&Asl[(wm + mt * 16 + l15) * 40 + quad * 8];
#pragma unroll
        for (int nt = 0; nt < 4; ++nt)
            bfr[nt] = *(const bf16x8*)&Bsl[(wn + nt * 16 + l15) * 40 + quad * 8];
#pragma unroll
        for (int mt = 0; mt < 4; ++mt)
#pragma unroll
            for (int nt = 0; nt < 4; ++nt)
                acc[mt][nt] = __builtin_amdgcn_mfma_f32_16x16x32_bf16(
                    af[mt], bfr[nt], acc[mt][nt], 0, 0, 0);
    }

    // epilogue: D lane mapping col=lane&15, row=quad*4+r  [m89-verified]
#pragma unroll
    for (int mt = 0; mt < 4; ++mt) {
#pragma unroll
        for (int nt = 0; nt < 4; ++nt) {
            int col  = n0 + wn + nt * 16 + l15;
            float bv = bias[col];
            int rowb = m0 + wm + mt * 16 + quad * 4;
#pragma unroll
            for (int r = 0; r < 4; ++r) {
                float v = acc[mt][nt][r] + bv;
                if (ACT == 1) v = v > 0.f ? v + 1.f : __expf(v);  // elu(x)+1
                if (ACT == 2) v = v > 0.f ? v : 0.f;              // relu
                C[(long long)(rowb + r) * O + col] = v;
            }
        }
    }
}

// ---------------------------------------------------------------------------
// KV / Ksum reduction: KV[n,h,m,d] = sum_s K[n,s,h*32+d] * V[n,s,h*32+m]
//                      KS[n,h,d]   = sum_s K[n,s,h*32+d]
// grid (L/512 chunks, NH, NB), block 256. Accumulate via atomics (pre-zeroed).
// ---------------------------------------------------------------------------
__global__ __launch_bounds__(256)
void kv_kernel(const float* __restrict__ Kg, const float* __restrict__ Vg,
               float* __restrict__ KV, float* __restrict__ KS)
{
    __shared__ float Ks[64 * 32];
    __shared__ float Vs[64 * 32];
    const int n = blockIdx.z, h = blockIdx.y;
    const int tid = threadIdx.x;
    const int d  = tid & 31;
    const int m4 = tid >> 5;   // 0..7, handles m = m4*4 + j

    float acc[4] = {0.f, 0.f, 0.f, 0.f};
    float ksum = 0.f;

    for (int sub = 0; sub < 8; ++sub) {
        int s0 = blockIdx.x * 512 + sub * 64;
        __syncthreads();
#pragma unroll
        for (int i = 0; i < 8; ++i) {
            int flat = tid + i * 256;      // 0..2047
            int tok  = flat >> 5;
            int dd   = flat & 31;
            long long gi = (long long)(n * LTOK + s0 + tok) * CDIM + h * HD + dd;
            Ks[tok * 32 + dd] = Kg[gi];
            Vs[tok * 32 + dd] = Vg[gi];
        }
        __syncthreads();
#pragma unroll 4
        for (int s = 0; s < 64; ++s) {
            float kd = Ks[s * 32 + d];
            if (m4 == 0) ksum += kd;
#pragma unroll
            for (int j = 0; j < 4; ++j)
                acc[j] += Vs[s * 32 + m4 * 4 + j] * kd;
        }
    }
#pragma unroll
    for (int j = 0; j < 4; ++j)
        atomicAdd(&KV[(((n * NH + h) * HD) + (m4 * 4 + j)) * HD + d], acc[j]);
    if (m4 == 0)
        atomicAdd(&KS[(n * NH + h) * HD + d], ksum);
}

// ---------------------------------------------------------------------------
// attn[n,l,h*32+m] = (sum_d Q[n,l,h,d]*KV[n,h,m,d]) / (sum_d Q[n,l,h,d]*KS[n,h,d] + eps)
// grid (L/64, NB), block 256; thread = (h = tid>>5, m = tid&31).
// ---------------------------------------------------------------------------
__global__ __launch_bounds__(256)
void attn_kernel(const float* __restrict__ Q, const float* __restrict__ KV,
                 const float* __restrict__ KS, float* __restrict__ out)
{
    __shared__ float kv_lds[NH * 32 * 33];   // [h][m*33 + d], padded
    __shared__ float ks_lds[NH * 32];
    __shared__ float q_lds[16 * 256];

    const int n = blockIdx.y;
    const int tid = threadIdx.x;
    const int h = tid >> 5;
    const int m = tid & 31;

    for (int i = tid; i < NH * 32 * 32; i += 256) {
        int hh  = i >> 10;
        int rem = i & 1023;
        int mm  = rem >> 5;
        int dd  = rem & 31;
        kv_lds[hh * 1056 + mm * 33 + dd] = KV[n * (NH * 32 * 32) + i];
    }
    ks_lds[tid] = KS[n * (NH * 32) + tid];
    __syncthreads();

    for (int it = 0; it < 4; ++it) {
        int l0 = blockIdx.x * 64 + it * 16;
#pragma unroll
        for (int i = 0; i < 16; ++i)
            q_lds[tid + i * 256] = Q[(long long)(n * LTOK + l0) * CDIM + tid + i * 256];
        __syncthreads();
        for (int t = 0; t < 16; ++t) {
            const float* qr = &q_lds[t * 256 + h * 32];
            const float* kvr = &kv_lds[h * 1056 + m * 33];
            const float* ksr = &ks_lds[h * 32];
            float den = 0.f, num = 0.f;
#pragma unroll
            for (int d = 0; d < 32; ++d) {
                float qd = qr[d];
                den += qd * ksr[d];
                num += qd * kvr[d];
            }
            out[(long long)(n * LTOK + l0 + t) * CDIM + tid] = num / (den + 1e-6f);
        }
        __syncthreads();
    }
}

// ---------------------------------------------------------------------------
// x = LayerNorm(x + t) * g + b   (in-place on x). One wave per token.
// grid MTOK/4 blocks, block 256 (4 waves).
// ---------------------------------------------------------------------------
__global__ __launch_bounds__(256)
void ln_kernel(float* __restrict__ X, const float* __restrict__ T,
               const float* __restrict__ g, const float* __restrict__ b)
{
    const int tid  = threadIdx.x;
    const int wave = tid >> 6;
    const int lane = tid & 63;
    const long long tok = (long long)blockIdx.x * 4 + wave;

    float4* X4 = (float4*)X;
    const float4* T4 = (const float4*)T;
    long long base = tok * 64 + lane;

    float4 xv = X4[base];
    float4 tv = T4[base];
    float4 v;
    v.x = xv.x + tv.x; v.y = xv.y + tv.y; v.z = xv.z + tv.z; v.w = xv.w + tv.w;

    float s = v.x + v.y + v.z + v.w;
#pragma unroll
    for (int off = 32; off > 0; off >>= 1) s += __shfl_xor(s, off, 64);
    float mean = s * (1.f / 256.f);

    float4 dv;
    dv.x = v.x - mean; dv.y = v.y - mean; dv.z = v.z - mean; dv.w = v.w - mean;
    float ss = dv.x * dv.x + dv.y * dv.y + dv.z * dv.z + dv.w * dv.w;
#pragma unroll
    for (int off = 32; off > 0; off >>= 1) ss += __shfl_xor(ss, off, 64);
    float rstd = rsqrtf(ss * (1.f / 256.f) + 1e-5f);

    const float4 gv = ((const float4*)g)[lane];
    const float4 bv = ((const float4*)b)[lane];
    float4 o;
    o.x = dv.x * rstd * gv.x + bv.x;
    o.y = dv.y * rstd * gv.y + bv.y;
    o.z = dv.z * rstd * gv.z + bv.z;
    o.w = dv.w * rstd * gv.w + bv.w;
    X4[base] = o;
}

// ---------------------------------------------------------------------------
// Launch
// ---------------------------------------------------------------------------
extern "C" void kernel_launch(void* const* d_in, const int* in_sizes, int n_in,
                              void* d_out, int out_size, void* d_ws, size_t ws_size,
                              hipStream_t stream)
{
    const float* ref = (const float*)d_in[0];
    const float* Wq  = (const float*)d_in[1];  const float* bq = (const float*)d_in[2];
    const float* Wk  = (const float*)d_in[3];  const float* bk = (const float*)d_in[4];
    const float* Wv  = (const float*)d_in[5];  const float* bv = (const float*)d_in[6];
    const float* Wo  = (const float*)d_in[7];  const float* bo = (const float*)d_in[8];
    const float* g1  = (const float*)d_in[9];  const float* be1 = (const float*)d_in[10];
    const float* W1  = (const float*)d_in[11]; const float* c1 = (const float*)d_in[12];
    const float* W2  = (const float*)d_in[13]; const float* c2 = (const float*)d_in[14];
    const float* g2  = (const float*)d_in[15]; const float* be2 = (const float*)d_in[16];
    float* out = (float*)d_out;

    // workspace layout (floats). SZ = 64 MiB worth of floats.
    const size_t SZ = (size_t)MTOK * CDIM;          // 16,777,216
    float* X    = (float*)d_ws;
    float* Qb   = X + SZ;
    float* Kb   = X + 2 * SZ;
    float* Vb   = X + 3 * SZ;
    float* KVb  = X + 4 * SZ;                        // NB*NH*32*32 = 32768
    float* KSb  = KVb + NB * NH * HD * HD;           // NB*NH*32   = 4096
    float* Hb   = Qb;                                // FF hidden aliases Q..K (2*SZ)
    // total: 4*SZ floats + 147 KB  ~= 256.1 MiB

    dim3 tb(32, 8);
    // patch embed: ref [n][C][HW] -> X [n][HW][C]
    transpose_k<<<dim3(HWDIM / 32, CDIM / 32, NB), tb, 0, stream>>>(
        ref, X, CDIM, HWDIM, (long long)CDIM * HWDIM, (long long)HWDIM * CDIM);

    for (int l = 0; l < NLAYER; ++l) {
        const float* Wq_l = Wq + (size_t)l * CDIM * CDIM;
        const float* Wk_l = Wk + (size_t)l * CDIM * CDIM;
        const float* Wv_l = Wv + (size_t)l * CDIM * CDIM;
        const float* Wo_l = Wo + (size_t)l * CDIM * CDIM;
        const float* W1_l = W1 + (size_t)l * FF * CDIM;
        const float* W2_l = W2 + (size_t)l * CDIM * FF;
        const float* bq_l = bq + (size_t)l * CDIM;
        const float* bk_l = bk + (size_t)l * CDIM;
        const float* bv_l = bv + (size_t)l * CDIM;
        const float* bo_l = bo + (size_t)l * CDIM;
        const float* c1_l = c1 + (size_t)l * FF;
        const float* c2_l = c2 + (size_t)l * CDIM;
        const float* g1_l = g1 + (size_t)l * CDIM;
        const float* g2_l = g2 + (size_t)l * CDIM;
        const float* be1_l = be1 + (size_t)l * CDIM;
        const float* be2_l = be2 + (size_t)l * CDIM;

        dim3 gC(MTOK / 128, CDIM / 128);   // O = 256
        dim3 gF(MTOK / 128, FF / 128);     // O = 512

        // Q = elu(x@Wq^T + bq)+1 ; K likewise ; V plain
        gemm_bias_act<1><<<gC, 256, 0, stream>>>(X, Wq_l, bq_l, Qb, MTOK, CDIM, CDIM);
        gemm_bias_act<1><<<gC, 256, 0, stream>>>(X, Wk_l, bk_l, Kb, MTOK, CDIM, CDIM);
        gemm_bias_act<0><<<gC, 256, 0, stream>>>(X, Wv_l, bv_l, Vb, MTOK, CDIM, CDIM);

        // KV + Ksum (zero first; ws is poisoned 0xAA each run)
        hipMemsetAsync(KVb, 0, (NB * NH * HD * HD + NB * NH * HD) * sizeof(float), stream);
        kv_kernel<<<dim3(LTOK / 512, NH, NB), 256, 0, stream>>>(Kb, Vb, KVb, KSb);

        // attn -> Kb (K dead), then proj -> Vb (V dead)
        attn_kernel<<<dim3(LTOK / 64, NB), 256, 0, stream>>>(Qb, KVb, KSb, Kb);
        gemm_bias_act<0><<<gC, 256, 0, stream>>>(Kb, Wo_l, bo_l, Vb, MTOK, CDIM, CDIM);

        // x = LN(x + attn_proj)
        ln_kernel<<<MTOK / 4, 256, 0, stream>>>(X, Vb, g1_l, be1_l);

        // FF: H = relu(x@W1^T + c1) -> aliases Q..K region; y = H@W2^T + c2 -> Vb
        gemm_bias_act<2><<<gF, 256, 0, stream>>>(X, W1_l, c1_l, Hb, MTOK, CDIM, FF);
        gemm_bias_act<0><<<gC, 256, 0, stream>>>(Hb, W2_l, c2_l, Vb, MTOK, FF, CDIM);

        // x = LN(x + y)
        ln_kernel<<<MTOK / 4, 256, 0, stream>>>(X, Vb, g2_l, be2_l);

        // layer output: X [n][L][C] -> out[l][n][C][L]
        transpose_k<<<dim3(CDIM / 32, LTOK / 32, NB), tb, 0, stream>>>(
            X, out + (size_t)l * NB * CDIM * LTOK,
            LTOK, CDIM, (long long)LTOK * CDIM, (long long)CDIM * LTOK);
    }
}

// Round 2
// 1692.698 us; speedup vs baseline: 1.2347x; 1.2347x over previous
//
#include <hip/hip_runtime.h>
#include <hip/hip_bf16.h>
#include <math.h>

#define NB     4
#define CDIM   256
#define HWDIM  16384
#define LTOK   16384
#define NH     8
#define HD     32
#define FF     512
#define MTOK   (NB * LTOK)
#define NLAYER 4

typedef __bf16 bf16x8 __attribute__((ext_vector_type(8)));
typedef __bf16 bf16x4 __attribute__((ext_vector_type(4)));
typedef float  floatx4 __attribute__((ext_vector_type(4)));

// async 16-B global->LDS copy; LDS dest = wave-uniform base + lane*16
#define GLD16(gp, lp)                                                        \
    __builtin_amdgcn_global_load_lds(                                        \
        (const __attribute__((address_space(1))) void*)(gp),                 \
        (__attribute__((address_space(3))) void*)(lp), 16, 0, 0)

// ---------------------------------------------------------------------------
// fp32 -> bf16 convert (weights, once)
// ---------------------------------------------------------------------------
__global__ __launch_bounds__(256)
void f2b_kernel(const float* __restrict__ in, __bf16* __restrict__ out)
{
    int i = (blockIdx.x * 256 + threadIdx.x) * 4;
    float4 f = *(const float4*)&in[i];
    bf16x4 h;
    h[0] = (__bf16)f.x; h[1] = (__bf16)f.y; h[2] = (__bf16)f.z; h[3] = (__bf16)f.w;
    *(bf16x4*)&out[i] = h;
}

// ---------------------------------------------------------------------------
// patch embed: ref fp32 [N,C,HW] -> X bf16 [N,HW,C]
// ---------------------------------------------------------------------------
__global__ __launch_bounds__(256)
void patch_embed(const float* __restrict__ in, __bf16* __restrict__ out)
{
    __shared__ float tile[32][33];
    const int n = blockIdx.z;
    const int hw0 = blockIdx.x * 32, c0 = blockIdx.y * 32;
    const int tx = threadIdx.x, ty = threadIdx.y;
#pragma unroll
    for (int i = 0; i < 32; i += 8)
        tile[ty + i][tx] = in[(long long)n * CDIM * HWDIM + (long long)(c0 + ty + i) * HWDIM + hw0 + tx];
    __syncthreads();
#pragma unroll
    for (int i = 0; i < 32; i += 8)
        out[(long long)(n * HWDIM + hw0 + ty + i) * CDIM + c0 + tx] = (__bf16)tile[tx][ty + i];
}

// ---------------------------------------------------------------------------
// output transpose: X bf16 [L,C] -> out fp32 [C,L] (per image n)
// ---------------------------------------------------------------------------
__global__ __launch_bounds__(256)
void out_transpose(const __bf16* __restrict__ X, float* __restrict__ out)
{
    __shared__ float tile[32][33];
    const int n = blockIdx.z;
    const int c0 = blockIdx.x * 32, l0 = blockIdx.y * 32;
    const int tx = threadIdx.x, ty = threadIdx.y;
#pragma unroll
    for (int i = 0; i < 32; i += 8)
        tile[ty + i][tx] = (float)X[(long long)(n * LTOK + l0 + ty + i) * CDIM + c0 + tx];
    __syncthreads();
#pragma unroll
    for (int i = 0; i < 32; i += 8)
        out[(long long)n * CDIM * LTOK + (long long)(c0 + ty + i) * LTOK + l0 + tx] = tile[tx][ty + i];
}

// ---------------------------------------------------------------------------
// MFMA bf16 GEMM (m97-style): C[M,O] = act(A[M,K] @ B[O,K]^T + bias[O])
// bf16 in / bf16 out, fp32 accumulate. 128x128 tile, BK=64, async LDS staging.
// ACT: 0 none, 1 elu+1, 2 relu
// ---------------------------------------------------------------------------
template <int ACT>
__global__ __launch_bounds__(256)
void gemm_bf16(const __bf16* __restrict__ A, const __bf16* __restrict__ B,
               const float* __restrict__ bias, __bf16* __restrict__ C,
               int M, int K, int O)
{
    // unpadded [row][k] rows of 64 bf16 (128 B) — required by global_load_lds
    __shared__ __bf16 Asl[128 * 64];
    __shared__ __bf16 Bsl[128 * 64];

    const int tid  = threadIdx.x;
    const int lane = tid & 63;
    const int wave = tid >> 6;
    const int m0   = blockIdx.x * 128;
    const int n0   = blockIdx.y * 128;
    const int l15  = lane & 15;
    const int quad = lane >> 4;
    const int wm   = (wave & 1) * 64;
    const int wn   = (wave >> 1) * 64;

    floatx4 acc[4][4];
#pragma unroll
    for (int i = 0; i < 4; ++i)
#pragma unroll
        for (int j = 0; j < 4; ++j)
            acc[i][j] = (floatx4){0.f, 0.f, 0.f, 0.f};

    for (int k0 = 0; k0 < K; k0 += 64) {
        __syncthreads();
        // stage A,B tiles: 1024 16-B slots each; slot s -> row s>>3, k-octet s&7
#pragma unroll
        for (int i = 0; i < 4; ++i) {
            int s   = wave * 256 + i * 64 + lane;
            int row = s >> 3, kq = s & 7;
            GLD16(&A[(long long)(m0 + row) * K + k0 + kq * 8],
                  &Asl[(wave * 256 + i * 64) * 8]);
        }
#pragma unroll
        for (int i = 0; i < 4; ++i) {
            int s   = wave * 256 + i * 64 + lane;
            int row = s >> 3, kq = s & 7;
            GLD16(&B[(long long)(n0 + row) * K + k0 + kq * 8],
                  &Bsl[(wave * 256 + i * 64) * 8]);
        }
        __syncthreads();

#pragma unroll
        for (int ko = 0; ko < 2; ++ko) {
            bf16x8 af[4], bfr[4];
#pragma unroll
            for (int mt = 0; mt < 4; ++mt)
                af[mt] = *(const bf16x8*)&Asl[(wm + mt * 16 + l15) * 64 + ko * 32 + quad * 8];
#pragma unroll
            for (int nt = 0; nt < 4; ++nt)
                bfr[nt] = *(const bf16x8*)&Bsl[(wn + nt * 16 + l15) * 64 + ko * 32 + quad * 8];
#pragma unroll
            for (int mt = 0; mt < 4; ++mt)
#pragma unroll
                for (int nt = 0; nt < 4; ++nt)
                    acc[mt][nt] = __builtin_amdgcn_mfma_f32_16x16x32_bf16(
                        af[mt], bfr[nt], acc[mt][nt], 0, 0, 0);
        }
    }

    // epilogue: D mapping col=lane&15, row=quad*4+r  [m89-verified]
#pragma unroll
    for (int mt = 0; mt < 4; ++mt) {
#pragma unroll
        for (int nt = 0; nt < 4; ++nt) {
            int col  = n0 + wn + nt * 16 + l15;
            float bv = bias[col];
            int rowb = m0 + wm + mt * 16 + quad * 4;
#pragma unroll
            for (int r = 0; r < 4; ++r) {
                float v = acc[mt][nt][r] + bv;
                if (ACT == 1) v = v > 0.f ? v + 1.f : __expf(v);
                if (ACT == 2) v = v > 0.f ? v : 0.f;
                C[(long long)(rowb + r) * O + col] = (__bf16)v;
            }
        }
    }
}

// ---------------------------------------------------------------------------
// KV[n,h,m,d] = sum_s K[n,s,h,d]*V[n,s,h,m]; KS[n,h,d] = sum_s K[n,s,h,d]
// ---------------------------------------------------------------------------
__global__ __launch_bounds__(256)
void kv_kernel(const __bf16* __restrict__ Kg, const __bf16* __restrict__ Vg,
               float* __restrict__ KV, float* __restrict__ KS)
{
    __shared__ float Ks[64 * 32];
    __shared__ float Vs[64 * 32];
    const int n = blockIdx.z, h = blockIdx.y;
    const int tid = threadIdx.x;
    const int d  = tid & 31;
    const int m4 = tid >> 5;

    float acc[4] = {0.f, 0.f, 0.f, 0.f};
    float ksum = 0.f;

    for (int sub = 0; sub < 8; ++sub) {
        int s0 = blockIdx.x * 512 + sub * 64;
        __syncthreads();
        {
            int e   = tid * 8;             // 2048 elems, 8 per thread, same token row
            int tok = e >> 5, dd = e & 31;
            long long gi = (long long)(n * LTOK + s0 + tok) * CDIM + h * HD + dd;
            bf16x8 kk = *(const bf16x8*)&Kg[gi];
            bf16x8 vv = *(const bf16x8*)&Vg[gi];
#pragma unroll
            for (int j = 0; j < 8; ++j) {
                Ks[e + j] = (float)kk[j];
                Vs[e + j] = (float)vv[j];
            }
        }
        __syncthreads();
#pragma unroll 4
        for (int s = 0; s < 64; ++s) {
            float kd = Ks[s * 32 + d];
            if (m4 == 0) ksum += kd;
#pragma unroll
            for (int j = 0; j < 4; ++j)
                acc[j] += Vs[s * 32 + m4 * 4 + j] * kd;
        }
    }
#pragma unroll
    for (int j = 0; j < 4; ++j)
        atomicAdd(&KV[(((n * NH + h) * HD) + (m4 * 4 + j)) * HD + d], acc[j]);
    if (m4 == 0)
        atomicAdd(&KS[(n * NH + h) * HD + d], ksum);
}

// ---------------------------------------------------------------------------
// attn[n,l,h,m] = (Q[n,l,h,:]·KV[n,h,m,:]) / (Q[n,l,h,:]·KS[n,h,:] + eps)
// ---------------------------------------------------------------------------
__global__ __launch_bounds__(256)
void attn_kernel(const __bf16* __restrict__ Q, const float* __restrict__ KV,
                 const float* __restrict__ KS, __bf16* __restrict__ out)
{
    __shared__ float kv_lds[NH * 32 * 33];
    __shared__ float ks_lds[NH * 32];
    __shared__ float q_lds[16 * 256];

    const int n = blockIdx.y;
    const int tid = threadIdx.x;
    const int h = tid >> 5;
    const int m = tid & 31;

    for (int i = tid; i < NH * 32 * 32; i += 256) {
        int hh  = i >> 10;
        int rem = i & 1023;
        int mm  = rem >> 5;
        int dd  = rem & 31;
        kv_lds[hh * 1056 + mm * 33 + dd] = KV[n * (NH * 32 * 32) + i];
    }
    ks_lds[tid] = KS[n * (NH * 32) + tid];
    __syncthreads();

    for (int it = 0; it < 4; ++it) {
        int l0 = blockIdx.x * 64 + it * 16;
#pragma unroll
        for (int i = 0; i < 4; ++i) {
            int e = tid * 4 + i * 1024;           // 4096 elems = 16 rows x 256
            int row = e >> 8, col = e & 255;
            bf16x4 q4 = *(const bf16x4*)&Q[(long long)(n * LTOK + l0 + row) * CDIM + col];
            float4 f;
            f.x = (float)q4[0]; f.y = (float)q4[1]; f.z = (float)q4[2]; f.w = (float)q4[3];
            *(float4*)&q_lds[e] = f;
        }
        __syncthreads();
        for (int t = 0; t < 16; ++t) {
            const float* qr  = &q_lds[t * 256 + h * 32];
            const float* kvr = &kv_lds[h * 1056 + m * 33];
            const float* ksr = &ks_lds[h * 32];
            float den = 0.f, num = 0.f;
#pragma unroll
            for (int d = 0; d < 32; ++d) {
                float qd = qr[d];
                den += qd * ksr[d];
                num += qd * kvr[d];
            }
            out[(long long)(n * LTOK + l0 + t) * CDIM + tid] = (__bf16)(num / (den + 1e-6f));
        }
        __syncthreads();
    }
}

// ---------------------------------------------------------------------------
// X = LayerNorm(X + T) * g + b   (bf16 in/out, fp32 math). One wave per token.
// ---------------------------------------------------------------------------
__global__ __launch_bounds__(256)
void ln_kernel(__bf16* __restrict__ X, const __bf16* __restrict__ T,
               const float* __restrict__ g, const float* __restrict__ b)
{
    const int tid  = threadIdx.x;
    const int wave = tid >> 6;
    const int lane = tid & 63;
    const long long tok = (long long)blockIdx.x * 4 + wave;
    const long long base = tok * CDIM + lane * 4;

    bf16x4 xv = *(const bf16x4*)&X[base];
    bf16x4 tv = *(const bf16x4*)&T[base];
    float v[4];
#pragma unroll
    for (int j = 0; j < 4; ++j) v[j] = (float)xv[j] + (float)tv[j];

    float s = v[0] + v[1] + v[2] + v[3];
#pragma unroll
    for (int off = 32; off > 0; off >>= 1) s += __shfl_xor(s, off, 64);
    float mean = s * (1.f / 256.f);

    float dv[4];
    float ss = 0.f;
#pragma unroll
    for (int j = 0; j < 4; ++j) { dv[j] = v[j] - mean; ss += dv[j] * dv[j]; }
#pragma unroll
    for (int off = 32; off > 0; off >>= 1) ss += __shfl_xor(ss, off, 64);
    float rstd = rsqrtf(ss * (1.f / 256.f) + 1e-5f);

    const float4 gv = ((const float4*)g)[lane];
    const float4 bv = ((const float4*)b)[lane];
    bf16x4 o;
    o[0] = (__bf16)(dv[0] * rstd * gv.x + bv.x);
    o[1] = (__bf16)(dv[1] * rstd * gv.y + bv.y);
    o[2] = (__bf16)(dv[2] * rstd * gv.z + bv.z);
    o[3] = (__bf16)(dv[3] * rstd * gv.w + bv.w);
    *(bf16x4*)&X[base] = o;
}

// ---------------------------------------------------------------------------
// Launch
// ---------------------------------------------------------------------------
extern "C" void kernel_launch(void* const* d_in, const int* in_sizes, int n_in,
                              void* d_out, int out_size, void* d_ws, size_t ws_size,
                              hipStream_t stream)
{
    const float* ref = (const float*)d_in[0];
    const float* Wq  = (const float*)d_in[1];  const float* bq = (const float*)d_in[2];
    const float* Wk  = (const float*)d_in[3];  const float* bk = (const float*)d_in[4];
    const float* Wv  = (const float*)d_in[5];  const float* bv = (const float*)d_in[6];
    const float* Wo  = (const float*)d_in[7];  const float* bo = (const float*)d_in[8];
    const float* g1  = (const float*)d_in[9];  const float* be1 = (const float*)d_in[10];
    const float* W1  = (const float*)d_in[11]; const float* c1 = (const float*)d_in[12];
    const float* W2  = (const float*)d_in[13]; const float* c2 = (const float*)d_in[14];
    const float* g2  = (const float*)d_in[15]; const float* be2 = (const float*)d_in[16];
    float* out = (float*)d_out;

    const size_t SZ = (size_t)MTOK * CDIM;   // 16,777,216 elements
    __bf16* Xb = (__bf16*)d_ws;              // 32 MB
    __bf16* Qb = Xb + SZ;
    __bf16* Kb = Qb + SZ;
    __bf16* Vb = Kb + SZ;
    __bf16* Hb = Vb + SZ;                    // MTOK*FF (64 MB)
    float*  KVb = (float*)(Hb + 2 * SZ);
    float*  KSb = KVb + NB * NH * HD * HD;
    __bf16* Wqb = (__bf16*)(KSb + NB * NH * HD);
    const size_t WC = (size_t)NLAYER * CDIM * CDIM;    // 262144
    const size_t WF = (size_t)NLAYER * FF * CDIM;      // 524288
    __bf16* Wkb = Wqb + WC;
    __bf16* Wvb = Wkb + WC;
    __bf16* Wob = Wvb + WC;
    __bf16* W1b = Wob + WC;
    __bf16* W2b = W1b + WF;

    // one-time weight conversion
    f2b_kernel<<<WC / 1024, 256, 0, stream>>>(Wq, Wqb);
    f2b_kernel<<<WC / 1024, 256, 0, stream>>>(Wk, Wkb);
    f2b_kernel<<<WC / 1024, 256, 0, stream>>>(Wv, Wvb);
    f2b_kernel<<<WC / 1024, 256, 0, stream>>>(Wo, Wob);
    f2b_kernel<<<WF / 1024, 256, 0, stream>>>(W1, W1b);
    f2b_kernel<<<WF / 1024, 256, 0, stream>>>(W2, W2b);

    dim3 tb(32, 8);
    patch_embed<<<dim3(HWDIM / 32, CDIM / 32, NB), tb, 0, stream>>>(ref, Xb);

    for (int l = 0; l < NLAYER; ++l) {
        const __bf16* Wq_l = Wqb + (size_t)l * CDIM * CDIM;
        const __bf16* Wk_l = Wkb + (size_t)l * CDIM * CDIM;
        const __bf16* Wv_l = Wvb + (size_t)l * CDIM * CDIM;
        const __bf16* Wo_l = Wob + (size_t)l * CDIM * CDIM;
        const __bf16* W1_l = W1b + (size_t)l * FF * CDIM;
        const __bf16* W2_l = W2b + (size_t)l * CDIM * FF;
        const float* bq_l = bq + (size_t)l * CDIM;
        const float* bk_l = bk + (size_t)l * CDIM;
        const float* bv_l = bv + (size_t)l * CDIM;
        const float* bo_l = bo + (size_t)l * CDIM;
        const float* c1_l = c1 + (size_t)l * FF;
        const float* c2_l = c2 + (size_t)l * CDIM;
        const float* g1_l = g1 + (size_t)l * CDIM;
        const float* g2_l = g2 + (size_t)l * CDIM;
        const float* be1_l = be1 + (size_t)l * CDIM;
        const float* be2_l = be2 + (size_t)l * CDIM;

        dim3 gC(MTOK / 128, CDIM / 128);
        dim3 gF(MTOK / 128, FF / 128);

        gemm_bf16<1><<<gC, 256, 0, stream>>>(Xb, Wq_l, bq_l, Qb, MTOK, CDIM, CDIM);
        gemm_bf16<1><<<gC, 256, 0, stream>>>(Xb, Wk_l, bk_l, Kb, MTOK, CDIM, CDIM);
        gemm_bf16<0><<<gC, 256, 0, stream>>>(Xb, Wv_l, bv_l, Vb, MTOK, CDIM, CDIM);

        hipMemsetAsync(KVb, 0, (NB * NH * HD * HD + NB * NH * HD) * sizeof(float), stream);
        kv_kernel<<<dim3(LTOK / 512, NH, NB), 256, 0, stream>>>(Kb, Vb, KVb, KSb);

        attn_kernel<<<dim3(LTOK / 64, NB), 256, 0, stream>>>(Qb, KVb, KSb, Kb);
        gemm_bf16<0><<<gC, 256, 0, stream>>>(Kb, Wo_l, bo_l, Vb, MTOK, CDIM, CDIM);

        ln_kernel<<<MTOK / 4, 256, 0, stream>>>(Xb, Vb, g1_l, be1_l);

        gemm_bf16<2><<<gF, 256, 0, stream>>>(Xb, W1_l, c1_l, Hb, MTOK, CDIM, FF);
        gemm_bf16<0><<<gC, 256, 0, stream>>>(Hb, W2_l, c2_l, Vb, MTOK, FF, CDIM);

        ln_kernel<<<MTOK / 4, 256, 0, stream>>>(Xb, Vb, g2_l, be2_l);

        out_transpose<<<dim3(CDIM / 32, LTOK / 32, NB), tb, 0, stream>>>(
            Xb, out + (size_t)l * NB * CDIM * LTOK);
    }
}

// Round 3
// 1656.706 us; speedup vs baseline: 1.2615x; 1.0217x over previous
//
#include <hip/hip_runtime.h>
#include <hip/hip_bf16.h>
#include <math.h>

#define NB     4
#define CDIM   256
#define HWDIM  16384
#define LTOK   16384
#define NH     8
#define HD     32
#define FF     512
#define MTOK   (NB * LTOK)
#define NLAYER 4

typedef __bf16 bf16x8 __attribute__((ext_vector_type(8)));
typedef __bf16 bf16x4 __attribute__((ext_vector_type(4)));
typedef float  floatx4 __attribute__((ext_vector_type(4)));

// async 16-B global->LDS copy; LDS dest = wave-uniform base + lane*16
#define GLD16(gp, lp)                                                        \
    __builtin_amdgcn_global_load_lds(                                        \
        (const __attribute__((address_space(1))) void*)(gp),                 \
        (__attribute__((address_space(3))) void*)(lp), 16, 0, 0)

// ---------------------------------------------------------------------------
// fp32 -> bf16 convert (weights, once)
// ---------------------------------------------------------------------------
__global__ __launch_bounds__(256)
void f2b_kernel(const float* __restrict__ in, __bf16* __restrict__ out)
{
    int i = (blockIdx.x * 256 + threadIdx.x) * 4;
    float4 f = *(const float4*)&in[i];
    bf16x4 h;
    h[0] = (__bf16)f.x; h[1] = (__bf16)f.y; h[2] = (__bf16)f.z; h[3] = (__bf16)f.w;
    *(bf16x4*)&out[i] = h;
}

// ---------------------------------------------------------------------------
// patch embed: ref fp32 [N,C,HW] -> X bf16 [N,HW,C]
// ---------------------------------------------------------------------------
__global__ __launch_bounds__(256)
void patch_embed(const float* __restrict__ in, __bf16* __restrict__ out)
{
    __shared__ float tile[32][33];
    const int n = blockIdx.z;
    const int hw0 = blockIdx.x * 32, c0 = blockIdx.y * 32;
    const int tx = threadIdx.x, ty = threadIdx.y;
#pragma unroll
    for (int i = 0; i < 32; i += 8)
        tile[ty + i][tx] = in[(long long)n * CDIM * HWDIM + (long long)(c0 + ty + i) * HWDIM + hw0 + tx];
    __syncthreads();
#pragma unroll
    for (int i = 0; i < 32; i += 8)
        out[(long long)(n * HWDIM + hw0 + ty + i) * CDIM + c0 + tx] = (__bf16)tile[tx][ty + i];
}

// ---------------------------------------------------------------------------
// output transpose: X bf16 [L,C] -> out fp32 [C,L]; one float4 store/thread
// ---------------------------------------------------------------------------
__global__ __launch_bounds__(256)
void out_transpose(const __bf16* __restrict__ X, float* __restrict__ out)
{
    __shared__ float tile[32][33];   // [l][c]
    const int n = blockIdx.z;
    const int c0 = blockIdx.x * 32, l0 = blockIdx.y * 32;
    const int tid = threadIdx.x;
    {
        int row = tid >> 3, cq = tid & 7;    // 32 l-rows x 8 col-quads
        bf16x4 x4 = *(const bf16x4*)&X[(long long)(n * LTOK + l0 + row) * CDIM + c0 + cq * 4];
#pragma unroll
        for (int j = 0; j < 4; ++j)
            tile[row][cq * 4 + j] = (float)x4[j];
    }
    __syncthreads();
    {
        int r = tid >> 3, lg = tid & 7;      // 32 c-rows x 8 l-quads
        float4 o;
        o.x = tile[lg * 4 + 0][r];
        o.y = tile[lg * 4 + 1][r];
        o.z = tile[lg * 4 + 2][r];
        o.w = tile[lg * 4 + 3][r];
        *(float4*)&out[(long long)n * CDIM * LTOK + (long long)(c0 + r) * LTOK + l0 + lg * 4] = o;
    }
}

// ---------------------------------------------------------------------------
// GEMM body macros: staging + MFMA (operands SWAPPED so D frag is row-major
// per thread: row = ...+l15, cols = ...+quad*4+r  -> packed bf16x4 stores)
// ---------------------------------------------------------------------------
#define GEMM_STAGE(Aq, Bq, Kdim)                                             \
    __syncthreads();                                                         \
    _Pragma("unroll")                                                        \
    for (int i = 0; i < 4; ++i) {                                            \
        int s = wave * 256 + i * 64 + lane;                                  \
        int row = s >> 3, kq = s & 7;                                        \
        GLD16(&(Aq)[(long long)(m0 + row) * (Kdim) + k0 + kq * 8],           \
              &Asl[(wave * 256 + i * 64) * 8]);                              \
    }                                                                        \
    _Pragma("unroll")                                                        \
    for (int i = 0; i < 4; ++i) {                                            \
        int s = wave * 256 + i * 64 + lane;                                  \
        int row = s >> 3, kq = s & 7;                                        \
        GLD16(&(Bq)[(long long)(n0 + row) * (Kdim) + k0 + kq * 8],           \
              &Bsl[(wave * 256 + i * 64) * 8]);                              \
    }                                                                        \
    __syncthreads();

#define GEMM_MFMA()                                                          \
    _Pragma("unroll")                                                        \
    for (int ko = 0; ko < 2; ++ko) {                                         \
        bf16x8 af[4], bfr[4];                                                \
        _Pragma("unroll")                                                    \
        for (int mt = 0; mt < 4; ++mt)                                       \
            af[mt] = *(const bf16x8*)&Asl[(wm + mt * 16 + l15) * 64 + ko * 32 + quad * 8]; \
        _Pragma("unroll")                                                    \
        for (int nt = 0; nt < 4; ++nt)                                       \
            bfr[nt] = *(const bf16x8*)&Bsl[(wn + nt * 16 + l15) * 64 + ko * 32 + quad * 8]; \
        _Pragma("unroll")                                                    \
        for (int mt = 0; mt < 4; ++mt)                                       \
            _Pragma("unroll")                                                \
            for (int nt = 0; nt < 4; ++nt)                                   \
                acc[mt][nt] = __builtin_amdgcn_mfma_f32_16x16x32_bf16(       \
                    bfr[nt], af[mt], acc[mt][nt], 0, 0, 0);                  \
    }

// ---------------------------------------------------------------------------
// generic GEMM: C[M,O] = act(A[M,K] @ B[O,K]^T + bias[O]); bf16 in/out
// ---------------------------------------------------------------------------
template <int ACT>
__global__ __launch_bounds__(256)
void gemm_bf16(const __bf16* __restrict__ A, const __bf16* __restrict__ B,
               const float* __restrict__ bias, __bf16* __restrict__ C,
               int M, int K, int O)
{
    __shared__ __bf16 Asl[128 * 64];
    __shared__ __bf16 Bsl[128 * 64];

    const int tid  = threadIdx.x;
    const int lane = tid & 63;
    const int wave = tid >> 6;
    const int m0   = blockIdx.x * 128;
    const int n0   = blockIdx.y * 128;
    const int l15  = lane & 15;
    const int quad = lane >> 4;
    const int wm   = (wave & 1) * 64;
    const int wn   = (wave >> 1) * 64;

    floatx4 acc[4][4];
#pragma unroll
    for (int i = 0; i < 4; ++i)
#pragma unroll
        for (int j = 0; j < 4; ++j)
            acc[i][j] = (floatx4){0.f, 0.f, 0.f, 0.f};

    for (int k0 = 0; k0 < K; k0 += 64) {
        GEMM_STAGE(A, B, K)
        GEMM_MFMA()
    }

#pragma unroll
    for (int mt = 0; mt < 4; ++mt) {
        int row = m0 + wm + mt * 16 + l15;
#pragma unroll
        for (int nt = 0; nt < 4; ++nt) {
            int col0 = n0 + wn + nt * 16 + quad * 4;
            float4 bb = *(const float4*)&bias[col0];
            bf16x4 o;
#pragma unroll
            for (int r = 0; r < 4; ++r) {
                float v = acc[mt][nt][r] + ((r == 0) ? bb.x : (r == 1) ? bb.y : (r == 2) ? bb.z : bb.w);
                if (ACT == 1) v = v > 0.f ? v + 1.f : __expf(v);
                if (ACT == 2) v = v > 0.f ? v : 0.f;
                o[r] = (__bf16)v;
            }
            *(bf16x4*)&C[(long long)row * O + col0] = o;
        }
    }
}

// ---------------------------------------------------------------------------
// fused QKV GEMM: grid.y in [0,6): sel = y>>1 picks {Q,K,V}, n0 = (y&1)*128
// ---------------------------------------------------------------------------
__global__ __launch_bounds__(256)
void gemm_qkv(const __bf16* __restrict__ X,
              const __bf16* __restrict__ Wq, const __bf16* __restrict__ Wk,
              const __bf16* __restrict__ Wv,
              const float* __restrict__ bq, const float* __restrict__ bk,
              const float* __restrict__ bv,
              __bf16* __restrict__ Qo, __bf16* __restrict__ Ko,
              __bf16* __restrict__ Vo)
{
    __shared__ __bf16 Asl[128 * 64];
    __shared__ __bf16 Bsl[128 * 64];

    const int sel = blockIdx.y >> 1;
    const __bf16* B    = (sel == 0) ? Wq : (sel == 1) ? Wk : Wv;
    const float*  bias = (sel == 0) ? bq : (sel == 1) ? bk : bv;
    __bf16*       C    = (sel == 0) ? Qo : (sel == 1) ? Ko : Vo;
    const bool do_elu  = sel < 2;

    const int tid  = threadIdx.x;
    const int lane = tid & 63;
    const int wave = tid >> 6;
    const int m0   = blockIdx.x * 128;
    const int n0   = (blockIdx.y & 1) * 128;
    const int l15  = lane & 15;
    const int quad = lane >> 4;
    const int wm   = (wave & 1) * 64;
    const int wn   = (wave >> 1) * 64;

    floatx4 acc[4][4];
#pragma unroll
    for (int i = 0; i < 4; ++i)
#pragma unroll
        for (int j = 0; j < 4; ++j)
            acc[i][j] = (floatx4){0.f, 0.f, 0.f, 0.f};

    for (int k0 = 0; k0 < CDIM; k0 += 64) {
        GEMM_STAGE(X, B, CDIM)
        GEMM_MFMA()
    }

#pragma unroll
    for (int mt = 0; mt < 4; ++mt) {
        int row = m0 + wm + mt * 16 + l15;
#pragma unroll
        for (int nt = 0; nt < 4; ++nt) {
            int col0 = n0 + wn + nt * 16 + quad * 4;
            float4 bb = *(const float4*)&bias[col0];
            bf16x4 o;
#pragma unroll
            for (int r = 0; r < 4; ++r) {
                float v = acc[mt][nt][r] + ((r == 0) ? bb.x : (r == 1) ? bb.y : (r == 2) ? bb.z : bb.w);
                if (do_elu) v = v > 0.f ? v + 1.f : __expf(v);
                o[r] = (__bf16)v;
            }
            *(bf16x4*)&C[(long long)row * CDIM + col0] = o;
        }
    }
}

// ---------------------------------------------------------------------------
// KV[n,h,m,d] = sum_s K[n,s,h,d]*V[n,s,h,m]; KS[n,h,d] = sum_s K[n,s,h,d]
// ---------------------------------------------------------------------------
__global__ __launch_bounds__(256)
void kv_kernel(const __bf16* __restrict__ Kg, const __bf16* __restrict__ Vg,
               float* __restrict__ KV, float* __restrict__ KS)
{
    __shared__ float Ks[64 * 32];
    __shared__ float Vs[64 * 32];
    const int n = blockIdx.z, h = blockIdx.y;
    const int tid = threadIdx.x;
    const int d  = tid & 31;
    const int m4 = tid >> 5;

    float acc[4] = {0.f, 0.f, 0.f, 0.f};
    float ksum = 0.f;

    for (int sub = 0; sub < 8; ++sub) {
        int s0 = blockIdx.x * 512 + sub * 64;
        __syncthreads();
        {
            int e   = tid * 8;
            int tok = e >> 5, dd = e & 31;
            long long gi = (long long)(n * LTOK + s0 + tok) * CDIM + h * HD + dd;
            bf16x8 kk = *(const bf16x8*)&Kg[gi];
            bf16x8 vv = *(const bf16x8*)&Vg[gi];
#pragma unroll
            for (int j = 0; j < 8; ++j) {
                Ks[e + j] = (float)kk[j];
                Vs[e + j] = (float)vv[j];
            }
        }
        __syncthreads();
#pragma unroll 4
        for (int s = 0; s < 64; ++s) {
            float kd = Ks[s * 32 + d];
            if (m4 == 0) ksum += kd;
#pragma unroll
            for (int j = 0; j < 4; ++j)
                acc[j] += Vs[s * 32 + m4 * 4 + j] * kd;
        }
    }
#pragma unroll
    for (int j = 0; j < 4; ++j)
        atomicAdd(&KV[(((n * NH + h) * HD) + (m4 * 4 + j)) * HD + d], acc[j]);
    if (m4 == 0)
        atomicAdd(&KS[(n * NH + h) * HD + d], ksum);
}

// ---------------------------------------------------------------------------
// attn[n,l,h,m] = (Q·KV row m) / (Q·KS + eps); KV/KS rows in REGISTERS
// ---------------------------------------------------------------------------
__global__ __launch_bounds__(256)
void attn_kernel(const __bf16* __restrict__ Q, const float* __restrict__ KV,
                 const float* __restrict__ KS, __bf16* __restrict__ out)
{
    __shared__ float q_lds[16 * 256];
    const int n = blockIdx.y;
    const int tid = threadIdx.x;
    const int h = tid >> 5;
    const int m = tid & 31;

    float4 kvr[8], ksr[8];
    {
        const float4* kvp = (const float4*)&KV[(((long long)n * NH + h) * HD + m) * HD];
        const float4* ksp = (const float4*)&KS[((long long)n * NH + h) * HD];
#pragma unroll
        for (int i = 0; i < 8; ++i) { kvr[i] = kvp[i]; ksr[i] = ksp[i]; }
    }

    for (int it = 0; it < 4; ++it) {
        int l0 = blockIdx.x * 64 + it * 16;
        __syncthreads();
#pragma unroll
        for (int i = 0; i < 4; ++i) {
            int e = tid * 4 + i * 1024;
            int row = e >> 8, col = e & 255;
            bf16x4 q4 = *(const bf16x4*)&Q[(long long)(n * LTOK + l0 + row) * CDIM + col];
            float4 f;
            f.x = (float)q4[0]; f.y = (float)q4[1]; f.z = (float)q4[2]; f.w = (float)q4[3];
            *(float4*)&q_lds[e] = f;
        }
        __syncthreads();
#pragma unroll 2
        for (int t = 0; t < 16; ++t) {
            const float4* qr = (const float4*)&q_lds[t * 256 + h * 32];
            float num = 0.f, den = 0.f;
#pragma unroll
            for (int i = 0; i < 8; ++i) {
                float4 q4 = qr[i];
                num += q4.x * kvr[i].x + q4.y * kvr[i].y + q4.z * kvr[i].z + q4.w * kvr[i].w;
                den += q4.x * ksr[i].x + q4.y * ksr[i].y + q4.z * ksr[i].z + q4.w * ksr[i].w;
            }
            out[(long long)(n * LTOK + l0 + t) * CDIM + tid] = (__bf16)(num / (den + 1e-6f));
        }
    }
}

// ---------------------------------------------------------------------------
// X = LayerNorm(X + T) * g + b   (bf16 in/out, fp32 math). One wave per token.
// ---------------------------------------------------------------------------
__global__ __launch_bounds__(256)
void ln_kernel(__bf16* __restrict__ X, const __bf16* __restrict__ T,
               const float* __restrict__ g, const float* __restrict__ b)
{
    const int tid  = threadIdx.x;
    const int wave = tid >> 6;
    const int lane = tid & 63;
    const long long tok = (long long)blockIdx.x * 4 + wave;
    const long long base = tok * CDIM + lane * 4;

    bf16x4 xv = *(const bf16x4*)&X[base];
    bf16x4 tv = *(const bf16x4*)&T[base];
    float v[4];
#pragma unroll
    for (int j = 0; j < 4; ++j) v[j] = (float)xv[j] + (float)tv[j];

    float s = v[0] + v[1] + v[2] + v[3];
#pragma unroll
    for (int off = 32; off > 0; off >>= 1) s += __shfl_xor(s, off, 64);
    float mean = s * (1.f / 256.f);

    float dv[4];
    float ss = 0.f;
#pragma unroll
    for (int j = 0; j < 4; ++j) { dv[j] = v[j] - mean; ss += dv[j] * dv[j]; }
#pragma unroll
    for (int off = 32; off > 0; off >>= 1) ss += __shfl_xor(ss, off, 64);
    float rstd = rsqrtf(ss * (1.f / 256.f) + 1e-5f);

    const float4 gv = ((const float4*)g)[lane];
    const float4 bv = ((const float4*)b)[lane];
    bf16x4 o;
    o[0] = (__bf16)(dv[0] * rstd * gv.x + bv.x);
    o[1] = (__bf16)(dv[1] * rstd * gv.y + bv.y);
    o[2] = (__bf16)(dv[2] * rstd * gv.z + bv.z);
    o[3] = (__bf16)(dv[3] * rstd * gv.w + bv.w);
    *(bf16x4*)&X[base] = o;
}

// ---------------------------------------------------------------------------
// Launch
// ---------------------------------------------------------------------------
extern "C" void kernel_launch(void* const* d_in, const int* in_sizes, int n_in,
                              void* d_out, int out_size, void* d_ws, size_t ws_size,
                              hipStream_t stream)
{
    const float* ref = (const float*)d_in[0];
    const float* Wq  = (const float*)d_in[1];  const float* bq = (const float*)d_in[2];
    const float* Wk  = (const float*)d_in[3];  const float* bk = (const float*)d_in[4];
    const float* Wv  = (const float*)d_in[5];  const float* bv = (const float*)d_in[6];
    const float* Wo  = (const float*)d_in[7];  const float* bo = (const float*)d_in[8];
    const float* g1  = (const float*)d_in[9];  const float* be1 = (const float*)d_in[10];
    const float* W1  = (const float*)d_in[11]; const float* c1 = (const float*)d_in[12];
    const float* W2  = (const float*)d_in[13]; const float* c2 = (const float*)d_in[14];
    const float* g2  = (const float*)d_in[15]; const float* be2 = (const float*)d_in[16];
    float* out = (float*)d_out;

    const size_t SZ = (size_t)MTOK * CDIM;
    __bf16* Xb = (__bf16*)d_ws;
    __bf16* Qb = Xb + SZ;
    __bf16* Kb = Qb + SZ;
    __bf16* Vb = Kb + SZ;
    __bf16* Hb = Vb + SZ;                    // MTOK*FF
    float*  KVb = (float*)(Hb + 2 * SZ);
    float*  KSb = KVb + NB * NH * HD * HD;
    __bf16* Wqb = (__bf16*)(KSb + NB * NH * HD);
    const size_t WC = (size_t)NLAYER * CDIM * CDIM;
    const size_t WF = (size_t)NLAYER * FF * CDIM;
    __bf16* Wkb = Wqb + WC;
    __bf16* Wvb = Wkb + WC;
    __bf16* Wob = Wvb + WC;
    __bf16* W1b = Wob + WC;
    __bf16* W2b = W1b + WF;

    f2b_kernel<<<WC / 1024, 256, 0, stream>>>(Wq, Wqb);
    f2b_kernel<<<WC / 1024, 256, 0, stream>>>(Wk, Wkb);
    f2b_kernel<<<WC / 1024, 256, 0, stream>>>(Wv, Wvb);
    f2b_kernel<<<WC / 1024, 256, 0, stream>>>(Wo, Wob);
    f2b_kernel<<<WF / 1024, 256, 0, stream>>>(W1, W1b);
    f2b_kernel<<<WF / 1024, 256, 0, stream>>>(W2, W2b);

    dim3 tb(32, 8);
    patch_embed<<<dim3(HWDIM / 32, CDIM / 32, NB), tb, 0, stream>>>(ref, Xb);

    for (int l = 0; l < NLAYER; ++l) {
        const __bf16* Wq_l = Wqb + (size_t)l * CDIM * CDIM;
        const __bf16* Wk_l = Wkb + (size_t)l * CDIM * CDIM;
        const __bf16* Wv_l = Wvb + (size_t)l * CDIM * CDIM;
        const __bf16* Wo_l = Wob + (size_t)l * CDIM * CDIM;
        const __bf16* W1_l = W1b + (size_t)l * FF * CDIM;
        const __bf16* W2_l = W2b + (size_t)l * CDIM * FF;
        const float* bq_l = bq + (size_t)l * CDIM;
        const float* bk_l = bk + (size_t)l * CDIM;
        const float* bv_l = bv + (size_t)l * CDIM;
        const float* bo_l = bo + (size_t)l * CDIM;
        const float* c1_l = c1 + (size_t)l * FF;
        const float* c2_l = c2 + (size_t)l * CDIM;
        const float* g1_l = g1 + (size_t)l * CDIM;
        const float* g2_l = g2 + (size_t)l * CDIM;
        const float* be1_l = be1 + (size_t)l * CDIM;
        const float* be2_l = be2 + (size_t)l * CDIM;

        dim3 gC(MTOK / 128, CDIM / 128);
        dim3 gF(MTOK / 128, FF / 128);

        gemm_qkv<<<dim3(MTOK / 128, 6), 256, 0, stream>>>(
            Xb, Wq_l, Wk_l, Wv_l, bq_l, bk_l, bv_l, Qb, Kb, Vb);

        hipMemsetAsync(KVb, 0, (NB * NH * HD * HD + NB * NH * HD) * sizeof(float), stream);
        kv_kernel<<<dim3(LTOK / 512, NH, NB), 256, 0, stream>>>(Kb, Vb, KVb, KSb);

        attn_kernel<<<dim3(LTOK / 64, NB), 256, 0, stream>>>(Qb, KVb, KSb, Kb);
        gemm_bf16<0><<<gC, 256, 0, stream>>>(Kb, Wo_l, bo_l, Vb, MTOK, CDIM, CDIM);

        ln_kernel<<<MTOK / 4, 256, 0, stream>>>(Xb, Vb, g1_l, be1_l);

        gemm_bf16<2><<<gF, 256, 0, stream>>>(Xb, W1_l, c1_l, Hb, MTOK, CDIM, FF);
        gemm_bf16<0><<<gC, 256, 0, stream>>>(Hb, W2_l, c2_l, Vb, MTOK, FF, CDIM);

        ln_kernel<<<MTOK / 4, 256, 0, stream>>>(Xb, Vb, g2_l, be2_l);

        out_transpose<<<dim3(CDIM / 32, LTOK / 32, NB), 256, 0, stream>>>(
            Xb, out + (size_t)l * NB * CDIM * LTOK);
    }
}

// Round 4
// 1454.976 us; speedup vs baseline: 1.4364x; 1.1386x over previous
//
#include <hip/hip_runtime.h>
#include <hip/hip_bf16.h>
#include <math.h>

#define NB     4
#define CDIM   256
#define HWDIM  16384
#define LTOK   16384
#define NH     8
#define HD     32
#define FF     512
#define MTOK   (NB * LTOK)
#define NLAYER 4

typedef __bf16 bf16x8 __attribute__((ext_vector_type(8)));
typedef __bf16 bf16x4 __attribute__((ext_vector_type(4)));
typedef float  floatx4 __attribute__((ext_vector_type(4)));

// async 16-B global->LDS copy; LDS dest = wave-uniform base + lane*16
#define GLD16(gp, lp)                                                        \
    __builtin_amdgcn_global_load_lds(                                        \
        (const __attribute__((address_space(1))) void*)(gp),                 \
        (__attribute__((address_space(3))) void*)(lp), 16, 0, 0)

// ---------------------------------------------------------------------------
// fp32 -> bf16 convert (weights, once)
// ---------------------------------------------------------------------------
__global__ __launch_bounds__(256)
void f2b_kernel(const float* __restrict__ in, __bf16* __restrict__ out)
{
    int i = (blockIdx.x * 256 + threadIdx.x) * 4;
    float4 f = *(const float4*)&in[i];
    bf16x4 h;
    h[0] = (__bf16)f.x; h[1] = (__bf16)f.y; h[2] = (__bf16)f.z; h[3] = (__bf16)f.w;
    *(bf16x4*)&out[i] = h;
}

// ---------------------------------------------------------------------------
// patch embed: ref fp32 [N,C,HW] -> X bf16 [N,HW,C]
// ---------------------------------------------------------------------------
__global__ __launch_bounds__(256)
void patch_embed(const float* __restrict__ in, __bf16* __restrict__ out)
{
    __shared__ float tile[32][33];
    const int n = blockIdx.z;
    const int hw0 = blockIdx.x * 32, c0 = blockIdx.y * 32;
    const int tx = threadIdx.x, ty = threadIdx.y;
#pragma unroll
    for (int i = 0; i < 32; i += 8)
        tile[ty + i][tx] = in[(long long)n * CDIM * HWDIM + (long long)(c0 + ty + i) * HWDIM + hw0 + tx];
    __syncthreads();
#pragma unroll
    for (int i = 0; i < 32; i += 8)
        out[(long long)(n * HWDIM + hw0 + ty + i) * CDIM + c0 + tx] = (__bf16)tile[tx][ty + i];
}

// ---------------------------------------------------------------------------
// output transpose: X bf16 [L,C] -> out fp32 [C,L]; one float4 store/thread
// ---------------------------------------------------------------------------
__global__ __launch_bounds__(256)
void out_transpose(const __bf16* __restrict__ X, float* __restrict__ out)
{
    __shared__ float tile[32][33];   // [l][c]
    const int n = blockIdx.z;
    const int c0 = blockIdx.x * 32, l0 = blockIdx.y * 32;
    const int tid = threadIdx.x;
    {
        int row = tid >> 3, cq = tid & 7;
        bf16x4 x4 = *(const bf16x4*)&X[(long long)(n * LTOK + l0 + row) * CDIM + c0 + cq * 4];
#pragma unroll
        for (int j = 0; j < 4; ++j)
            tile[row][cq * 4 + j] = (float)x4[j];
    }
    __syncthreads();
    {
        int r = tid >> 3, lg = tid & 7;
        float4 o;
        o.x = tile[lg * 4 + 0][r];
        o.y = tile[lg * 4 + 1][r];
        o.z = tile[lg * 4 + 2][r];
        o.w = tile[lg * 4 + 3][r];
        *(float4*)&out[(long long)n * CDIM * LTOK + (long long)(c0 + r) * LTOK + l0 + lg * 4] = o;
    }
}

// ---------------------------------------------------------------------------
// Wide GEMM core: 128 (tokens) x 256 (full output width) tile, BK=64.
// 4 waves: wm=(wave&1)*64, wn=(wave>>1)*128. Frags 4(mt) x 8(nt).
// Operands swapped in MFMA so D frag is row-major per thread
// (row = ...+l15, cols = ...+quad*4+r) -> packed bf16x4 stores [R3-verified].
// ---------------------------------------------------------------------------
#define WIDE_PROLOGUE()                                                      \
    const int tid  = threadIdx.x;                                            \
    const int lane = tid & 63;                                               \
    const int wave = tid >> 6;                                               \
    const int m0   = blockIdx.x * 128;                                       \
    const int l15  = lane & 15;                                              \
    const int quad = lane >> 4;                                              \
    const int wm   = (wave & 1) * 64;                                        \
    const int wn   = (wave >> 1) * 128;                                      \
    floatx4 acc[4][8];                                                       \
    _Pragma("unroll")                                                        \
    for (int i = 0; i < 4; ++i)                                              \
        _Pragma("unroll")                                                    \
        for (int j = 0; j < 8; ++j)                                          \
            acc[i][j] = (floatx4){0.f, 0.f, 0.f, 0.f};

#define WIDE_STAGE(Aq, Bq, KD)                                               \
    __syncthreads();                                                         \
    _Pragma("unroll")                                                        \
    for (int i = 0; i < 4; ++i) {                                            \
        int s = wave * 256 + i * 64 + lane;                                  \
        int row = s >> 3, kq = s & 7;                                        \
        GLD16(&(Aq)[(long long)(m0 + row) * (KD) + k0 + kq * 8],             \
              &Asl[(wave * 256 + i * 64) * 8]);                              \
    }                                                                        \
    _Pragma("unroll")                                                        \
    for (int i = 0; i < 8; ++i) {                                            \
        int s = wave * 512 + i * 64 + lane;                                  \
        int row = s >> 3, kq = s & 7;                                        \
        GLD16(&(Bq)[(long long)row * (KD) + k0 + kq * 8],                    \
              &Bsl[(wave * 512 + i * 64) * 8]);                              \
    }                                                                        \
    __syncthreads();

#define WIDE_MFMA()                                                          \
    _Pragma("unroll")                                                        \
    for (int ko = 0; ko < 2; ++ko) {                                         \
        bf16x8 af[4], bfr[8];                                                \
        _Pragma("unroll")                                                    \
        for (int mt = 0; mt < 4; ++mt)                                       \
            af[mt] = *(const bf16x8*)&Asl[(wm + mt * 16 + l15) * 64 + ko * 32 + quad * 8]; \
        _Pragma("unroll")                                                    \
        for (int nt = 0; nt < 8; ++nt)                                       \
            bfr[nt] = *(const bf16x8*)&Bsl[(wn + nt * 16 + l15) * 64 + ko * 32 + quad * 8]; \
        _Pragma("unroll")                                                    \
        for (int mt = 0; mt < 4; ++mt)                                       \
            _Pragma("unroll")                                                \
            for (int nt = 0; nt < 8; ++nt)                                   \
                acc[mt][nt] = __builtin_amdgcn_mfma_f32_16x16x32_bf16(       \
                    bfr[nt], af[mt], acc[mt][nt], 0, 0, 0);                  \
    }

// ---------------------------------------------------------------------------
// fused QKV: grid (MTOK/128, 3); sel picks {Q,K,V}; elu+1 on Q,K
// ---------------------------------------------------------------------------
__global__ __launch_bounds__(256, 2)
void gemm_qkv(const __bf16* __restrict__ X,
              const __bf16* __restrict__ Wq, const __bf16* __restrict__ Wk,
              const __bf16* __restrict__ Wv,
              const float* __restrict__ bq, const float* __restrict__ bk,
              const float* __restrict__ bv,
              __bf16* __restrict__ Qo, __bf16* __restrict__ Ko,
              __bf16* __restrict__ Vo)
{
    __shared__ __bf16 Asl[128 * 64];
    __shared__ __bf16 Bsl[256 * 64];
    const int sel = blockIdx.y;
    const __bf16* B    = (sel == 0) ? Wq : (sel == 1) ? Wk : Wv;
    const float*  bias = (sel == 0) ? bq : (sel == 1) ? bk : bv;
    __bf16*       C    = (sel == 0) ? Qo : (sel == 1) ? Ko : Vo;
    const bool do_elu  = sel < 2;

    WIDE_PROLOGUE()
    for (int k0 = 0; k0 < CDIM; k0 += 64) {
        WIDE_STAGE(X, B, CDIM)
        WIDE_MFMA()
    }
#pragma unroll
    for (int mt = 0; mt < 4; ++mt) {
        int row = m0 + wm + mt * 16 + l15;
#pragma unroll
        for (int nt = 0; nt < 8; ++nt) {
            int col0 = wn + nt * 16 + quad * 4;
            float4 bb = *(const float4*)&bias[col0];
            bf16x4 o;
#pragma unroll
            for (int r = 0; r < 4; ++r) {
                float v = acc[mt][nt][r] + ((r == 0) ? bb.x : (r == 1) ? bb.y : (r == 2) ? bb.z : bb.w);
                if (do_elu) v = v > 0.f ? v + 1.f : __expf(v);
                o[r] = (__bf16)v;
            }
            *(bf16x4*)&C[(long long)row * CDIM + col0] = o;
        }
    }
}

// ---------------------------------------------------------------------------
// W1 GEMM + ReLU: grid (MTOK/128, 2); n_base = blockIdx.y*256; O=512, K=256
// ---------------------------------------------------------------------------
__global__ __launch_bounds__(256, 2)
void gemm_relu(const __bf16* __restrict__ A, const __bf16* __restrict__ Bw,
               const float* __restrict__ bias, __bf16* __restrict__ C)
{
    __shared__ __bf16 Asl[128 * 64];
    __shared__ __bf16 Bsl[256 * 64];
    const int n_base = blockIdx.y * 256;
    const __bf16* B = Bw + (long long)n_base * CDIM;

    WIDE_PROLOGUE()
    for (int k0 = 0; k0 < CDIM; k0 += 64) {
        WIDE_STAGE(A, B, CDIM)
        WIDE_MFMA()
    }
#pragma unroll
    for (int mt = 0; mt < 4; ++mt) {
        int row = m0 + wm + mt * 16 + l15;
#pragma unroll
        for (int nt = 0; nt < 8; ++nt) {
            int col0 = wn + nt * 16 + quad * 4;
            float4 bb = *(const float4*)&bias[n_base + col0];
            bf16x4 o;
#pragma unroll
            for (int r = 0; r < 4; ++r) {
                float v = acc[mt][nt][r] + ((r == 0) ? bb.x : (r == 1) ? bb.y : (r == 2) ? bb.z : bb.w);
                o[r] = (__bf16)(v > 0.f ? v : 0.f);
            }
            *(bf16x4*)&C[(long long)row * FF + n_base + col0] = o;
        }
    }
}

// ---------------------------------------------------------------------------
// GEMM + residual + LayerNorm fused:  X = LN(X + A@B^T + bias) * g + be
// Full-width 128x256 tile => block owns whole token rows. X updated in place.
// ---------------------------------------------------------------------------
template <int KDIM>
__global__ __launch_bounds__(256, 2)
void gemm_ln(const __bf16* __restrict__ A, const __bf16* __restrict__ B,
             const float* __restrict__ bias, __bf16* X,
             const float* __restrict__ g, const float* __restrict__ be)
{
    __shared__ __bf16 Asl[128 * 64];
    __shared__ __bf16 Bsl[256 * 64];

    WIDE_PROLOGUE()
    for (int k0 = 0; k0 < KDIM; k0 += 64) {
        WIDE_STAGE(A, B, KDIM)
        WIDE_MFMA()
    }

    // bias + residual into fp32 acc
#pragma unroll
    for (int mt = 0; mt < 4; ++mt) {
        int row = m0 + wm + mt * 16 + l15;
#pragma unroll
        for (int nt = 0; nt < 8; ++nt) {
            int col0 = wn + nt * 16 + quad * 4;
            float4 bb = *(const float4*)&bias[col0];
            bf16x4 xr = *(const bf16x4*)&X[(long long)row * CDIM + col0];
            acc[mt][nt][0] += bb.x + (float)xr[0];
            acc[mt][nt][1] += bb.y + (float)xr[1];
            acc[mt][nt][2] += bb.z + (float)xr[2];
            acc[mt][nt][3] += bb.w + (float)xr[3];
        }
    }

    // per-row sums over this wave's 128-col half: reduce quads via shfl
    float psum[4], psq[4];
#pragma unroll
    for (int mt = 0; mt < 4; ++mt) {
        float s = 0.f, q = 0.f;
#pragma unroll
        for (int nt = 0; nt < 8; ++nt)
#pragma unroll
            for (int r = 0; r < 4; ++r) {
                float v = acc[mt][nt][r];
                s += v; q += v * v;
            }
        s += __shfl_xor(s, 16, 64); s += __shfl_xor(s, 32, 64);
        q += __shfl_xor(q, 16, 64); q += __shfl_xor(q, 32, 64);
        psum[mt] = s; psq[mt] = q;
    }

    // cross-wave reduction through LDS (aliases Asl; barrier first)
    float* red = (float*)Asl;           // red[row_local*4 + half*2 + {0,1}]
    const int half = wave >> 1;
    __syncthreads();
    if (quad == 0) {
#pragma unroll
        for (int mt = 0; mt < 4; ++mt) {
            int rl = wm + mt * 16 + l15;
            red[rl * 4 + half * 2 + 0] = psum[mt];
            red[rl * 4 + half * 2 + 1] = psq[mt];
        }
    }
    __syncthreads();

    // normalize + store
#pragma unroll
    for (int mt = 0; mt < 4; ++mt) {
        int rl  = wm + mt * 16 + l15;
        float tot = red[rl * 4 + 0] + red[rl * 4 + 2];
        float tsq = red[rl * 4 + 1] + red[rl * 4 + 3];
        float mean = tot * (1.f / 256.f);
        float var  = tsq * (1.f / 256.f) - mean * mean;
        float rstd = rsqrtf(var + 1e-5f);
        int row = m0 + rl;
#pragma unroll
        for (int nt = 0; nt < 8; ++nt) {
            int col0 = wn + nt * 16 + quad * 4;
            float4 gg = *(const float4*)&g[col0];
            float4 ee = *(const float4*)&be[col0];
            bf16x4 o;
            o[0] = (__bf16)((acc[mt][nt][0] - mean) * rstd * gg.x + ee.x);
            o[1] = (__bf16)((acc[mt][nt][1] - mean) * rstd * gg.y + ee.y);
            o[2] = (__bf16)((acc[mt][nt][2] - mean) * rstd * gg.z + ee.z);
            o[3] = (__bf16)((acc[mt][nt][3] - mean) * rstd * gg.w + ee.w);
            *(bf16x4*)&X[(long long)row * CDIM + col0] = o;
        }
    }
}

// ---------------------------------------------------------------------------
// KV[n,h,m,d] = sum_s K[n,s,h,d]*V[n,s,h,m]; KS[n,h,d] = sum_s K[n,s,h,d]
// ---------------------------------------------------------------------------
__global__ __launch_bounds__(256)
void kv_kernel(const __bf16* __restrict__ Kg, const __bf16* __restrict__ Vg,
               float* __restrict__ KV, float* __restrict__ KS)
{
    __shared__ float Ks[64 * 32];
    __shared__ float Vs[64 * 32];
    const int n = blockIdx.z, h = blockIdx.y;
    const int tid = threadIdx.x;
    const int d  = tid & 31;
    const int m4 = tid >> 5;

    float acc[4] = {0.f, 0.f, 0.f, 0.f};
    float ksum = 0.f;

    for (int sub = 0; sub < 8; ++sub) {
        int s0 = blockIdx.x * 512 + sub * 64;
        __syncthreads();
        {
            int e   = tid * 8;
            int tok = e >> 5, dd = e & 31;
            long long gi = (long long)(n * LTOK + s0 + tok) * CDIM + h * HD + dd;
            bf16x8 kk = *(const bf16x8*)&Kg[gi];
            bf16x8 vv = *(const bf16x8*)&Vg[gi];
#pragma unroll
            for (int j = 0; j < 8; ++j) {
                Ks[e + j] = (float)kk[j];
                Vs[e + j] = (float)vv[j];
            }
        }
        __syncthreads();
#pragma unroll 4
        for (int s = 0; s < 64; ++s) {
            float kd = Ks[s * 32 + d];
            if (m4 == 0) ksum += kd;
#pragma unroll
            for (int j = 0; j < 4; ++j)
                acc[j] += Vs[s * 32 + m4 * 4 + j] * kd;
        }
    }
#pragma unroll
    for (int j = 0; j < 4; ++j)
        atomicAdd(&KV[(((n * NH + h) * HD) + (m4 * 4 + j)) * HD + d], acc[j]);
    if (m4 == 0)
        atomicAdd(&KS[(n * NH + h) * HD + d], ksum);
}

// ---------------------------------------------------------------------------
// attn[n,l,h,m] = (Q·KV row m) / (Q·KS + eps); KV/KS rows in registers
// ---------------------------------------------------------------------------
__global__ __launch_bounds__(256)
void attn_kernel(const __bf16* __restrict__ Q, const float* __restrict__ KV,
                 const float* __restrict__ KS, __bf16* __restrict__ out)
{
    __shared__ float q_lds[16 * 256];
    const int n = blockIdx.y;
    const int tid = threadIdx.x;
    const int h = tid >> 5;
    const int m = tid & 31;

    float4 kvr[8], ksr[8];
    {
        const float4* kvp = (const float4*)&KV[(((long long)n * NH + h) * HD + m) * HD];
        const float4* ksp = (const float4*)&KS[((long long)n * NH + h) * HD];
#pragma unroll
        for (int i = 0; i < 8; ++i) { kvr[i] = kvp[i]; ksr[i] = ksp[i]; }
    }

    for (int it = 0; it < 4; ++it) {
        int l0 = blockIdx.x * 64 + it * 16;
        __syncthreads();
#pragma unroll
        for (int i = 0; i < 4; ++i) {
            int e = tid * 4 + i * 1024;
            int row = e >> 8, col = e & 255;
            bf16x4 q4 = *(const bf16x4*)&Q[(long long)(n * LTOK + l0 + row) * CDIM + col];
            float4 f;
            f.x = (float)q4[0]; f.y = (float)q4[1]; f.z = (float)q4[2]; f.w = (float)q4[3];
            *(float4*)&q_lds[e] = f;
        }
        __syncthreads();
#pragma unroll 2
        for (int t = 0; t < 16; ++t) {
            const float4* qr = (const float4*)&q_lds[t * 256 + h * 32];
            float num = 0.f, den = 0.f;
#pragma unroll
            for (int i = 0; i < 8; ++i) {
                float4 q4 = qr[i];
                num += q4.x * kvr[i].x + q4.y * kvr[i].y + q4.z * kvr[i].z + q4.w * kvr[i].w;
                den += q4.x * ksr[i].x + q4.y * ksr[i].y + q4.z * ksr[i].z + q4.w * ksr[i].w;
            }
            out[(long long)(n * LTOK + l0 + t) * CDIM + tid] = (__bf16)(num / (den + 1e-6f));
        }
    }
}

// ---------------------------------------------------------------------------
// Launch
// ---------------------------------------------------------------------------
extern "C" void kernel_launch(void* const* d_in, const int* in_sizes, int n_in,
                              void* d_out, int out_size, void* d_ws, size_t ws_size,
                              hipStream_t stream)
{
    const float* ref = (const float*)d_in[0];
    const float* Wq  = (const float*)d_in[1];  const float* bq = (const float*)d_in[2];
    const float* Wk  = (const float*)d_in[3];  const float* bk = (const float*)d_in[4];
    const float* Wv  = (const float*)d_in[5];  const float* bv = (const float*)d_in[6];
    const float* Wo  = (const float*)d_in[7];  const float* bo = (const float*)d_in[8];
    const float* g1  = (const float*)d_in[9];  const float* be1 = (const float*)d_in[10];
    const float* W1  = (const float*)d_in[11]; const float* c1 = (const float*)d_in[12];
    const float* W2  = (const float*)d_in[13]; const float* c2 = (const float*)d_in[14];
    const float* g2  = (const float*)d_in[15]; const float* be2 = (const float*)d_in[16];
    float* out = (float*)d_out;

    const size_t SZ = (size_t)MTOK * CDIM;
    __bf16* Xb = (__bf16*)d_ws;
    __bf16* Qb = Xb + SZ;
    __bf16* Kb = Qb + SZ;
    __bf16* Vb = Kb + SZ;
    __bf16* Hb = Vb + SZ;                    // MTOK*FF
    float*  KVb = (float*)(Hb + 2 * SZ);
    float*  KSb = KVb + NB * NH * HD * HD;
    __bf16* Wqb = (__bf16*)(KSb + NB * NH * HD);
    const size_t WC = (size_t)NLAYER * CDIM * CDIM;
    const size_t WF = (size_t)NLAYER * FF * CDIM;
    __bf16* Wkb = Wqb + WC;
    __bf16* Wvb = Wkb + WC;
    __bf16* Wob = Wvb + WC;
    __bf16* W1b = Wob + WC;
    __bf16* W2b = W1b + WF;

    f2b_kernel<<<WC / 1024, 256, 0, stream>>>(Wq, Wqb);
    f2b_kernel<<<WC / 1024, 256, 0, stream>>>(Wk, Wkb);
    f2b_kernel<<<WC / 1024, 256, 0, stream>>>(Wv, Wvb);
    f2b_kernel<<<WC / 1024, 256, 0, stream>>>(Wo, Wob);
    f2b_kernel<<<WF / 1024, 256, 0, stream>>>(W1, W1b);
    f2b_kernel<<<WF / 1024, 256, 0, stream>>>(W2, W2b);

    dim3 tb(32, 8);
    patch_embed<<<dim3(HWDIM / 32, CDIM / 32, NB), tb, 0, stream>>>(ref, Xb);

    for (int l = 0; l < NLAYER; ++l) {
        const __bf16* Wq_l = Wqb + (size_t)l * CDIM * CDIM;
        const __bf16* Wk_l = Wkb + (size_t)l * CDIM * CDIM;
        const __bf16* Wv_l = Wvb + (size_t)l * CDIM * CDIM;
        const __bf16* Wo_l = Wob + (size_t)l * CDIM * CDIM;
        const __bf16* W1_l = W1b + (size_t)l * FF * CDIM;
        const __bf16* W2_l = W2b + (size_t)l * CDIM * FF;
        const float* bq_l = bq + (size_t)l * CDIM;
        const float* bk_l = bk + (size_t)l * CDIM;
        const float* bv_l = bv + (size_t)l * CDIM;
        const float* bo_l = bo + (size_t)l * CDIM;
        const float* c1_l = c1 + (size_t)l * FF;
        const float* c2_l = c2 + (size_t)l * CDIM;
        const float* g1_l = g1 + (size_t)l * CDIM;
        const float* g2_l = g2 + (size_t)l * CDIM;
        const float* be1_l = be1 + (size_t)l * CDIM;
        const float* be2_l = be2 + (size_t)l * CDIM;

        gemm_qkv<<<dim3(MTOK / 128, 3), 256, 0, stream>>>(
            Xb, Wq_l, Wk_l, Wv_l, bq_l, bk_l, bv_l, Qb, Kb, Vb);

        hipMemsetAsync(KVb, 0, (NB * NH * HD * HD + NB * NH * HD) * sizeof(float), stream);
        kv_kernel<<<dim3(LTOK / 512, NH, NB), 256, 0, stream>>>(Kb, Vb, KVb, KSb);

        attn_kernel<<<dim3(LTOK / 64, NB), 256, 0, stream>>>(Qb, KVb, KSb, Kb);

        // X = LN(X + attn@Wo^T + bo)
        gemm_ln<CDIM><<<MTOK / 128, 256, 0, stream>>>(Kb, Wo_l, bo_l, Xb, g1_l, be1_l);

        // H = relu(X@W1^T + c1)
        gemm_relu<<<dim3(MTOK / 128, 2), 256, 0, stream>>>(Xb, W1_l, c1_l, Hb);

        // X = LN(X + H@W2^T + c2)
        gemm_ln<FF><<<MTOK / 128, 256, 0, stream>>>(Hb, W2_l, c2_l, Xb, g2_l, be2_l);

        out_transpose<<<dim3(CDIM / 32, LTOK / 32, NB), 256, 0, stream>>>(
            Xb, out + (size_t)l * NB * CDIM * LTOK);
    }
}